// Round 12
// baseline (14436.983 us; speedup 1.0000x reference)
//
#include <hip/hip_runtime.h>

typedef __bf16 bf16x8 __attribute__((ext_vector_type(8)));
typedef float  f32x4  __attribute__((ext_vector_type(4)));
typedef unsigned short u16;
typedef unsigned int   u32;
typedef unsigned long long u64;

#define NB 128
#define NT 1024
#define NF 128
#define NH 256
#define NG 1024
#define D  32                  // ring depth (steps), power of 2
#define SENT64 (~0ull)
#define SENTF  0xFFFFFFFFu

// flags (u32 offsets, 64B-padded lanes)
#define F_PROG1(g)  ((g)*16)            // L1-rec: ring1 consumed+wiped count
#define F_PROG2(g)  (128+(g)*16)        // L2-rec: ring2 consumed+wiped count
#define F_CP(g,p)   (256+(g)*32+(p)*16) // xw2-prod consume progress
#define F_HWIPE(g)  (512+(g)*16)        // hring wiped count (by xw2 p=0)
#define FLAGS_N 1024

__device__ __forceinline__ u16 f2bf(float f){ union{float f;u32 u;}c;c.f=f;u32 u=c.u;return (u16)((u+0x7fffu+((u>>16)&1u))>>16);}
__device__ __forceinline__ float sigm(float x){return 1.f/(1.f+__expf(-x));}
__device__ __forceinline__ float tanh_(float x){return 1.f-2.f/(1.f+__expf(2.f*x));}
__device__ __forceinline__ f32x4 mm(bf16x8 a,bf16x8 b,f32x4 c){return __builtin_amdgcn_mfma_f32_16x16x32_bf16(a,b,c,0,0,0);}
__device__ __forceinline__ u32 a_ld32(const u32*p){return __hip_atomic_load((u32*)p,__ATOMIC_RELAXED,__HIP_MEMORY_SCOPE_AGENT);}
__device__ __forceinline__ u64 a_ld64(const u64*p){return __hip_atomic_load((u64*)p,__ATOMIC_RELAXED,__HIP_MEMORY_SCOPE_AGENT);}
__device__ __forceinline__ void a_st32(u32*p,u32 v){__hip_atomic_store(p,v,__ATOMIC_RELAXED,__HIP_MEMORY_SCOPE_AGENT);}
__device__ __forceinline__ void a_st64(u64*p,u64 v){__hip_atomic_store(p,v,__ATOMIC_RELAXED,__HIP_MEMORY_SCOPE_AGENT);}
__device__ __forceinline__ void vmw(){asm volatile("s_waitcnt vmcnt(0)":::"memory");}

// ---------------------------------------------------------------------------
// prep_pack: weights fp32 -> bf16 MFMA B-fragments, frag-linear layout
// [fi][lane][8]. U frags fi = ((kt*4+w)*4+gg)*4+ct (col = gg*256+w*64+ct*16+l15).
// W1 frags fi = (kt*4+w)*16+nt (col = w*256+nt*16+l15, K=128).
// W2 frags fi = ((p*8+kt)*4+w)*8+nt (col = p*512+w*128+nt*16+l15, K=256).
// ---------------------------------------------------------------------------
__global__ void prep_pack(const float* __restrict__ U1,const float* __restrict__ U2,
                          const float* __restrict__ W1,const float* __restrict__ W2,
                          u16* __restrict__ U1p,u16* __restrict__ U2p,
                          u16* __restrict__ W1p,u16* __restrict__ W2p){
  int i = blockIdx.x*256+threadIdx.x;
  if (i < 32768) {                       // U frags (both layers), 512 frags
    int lane=i&63, fi=i>>6;
    int ct=fi&3, gg=(fi>>2)&3, w=(fi>>4)&3, kt=fi>>6;
    int col = gg*256 + w*64 + ct*16 + (lane&15);
    int k0  = kt*32 + (lane>>4)*8;
    u16* o1 = U1p + (size_t)fi*512 + lane*8;
    u16* o2 = U2p + (size_t)fi*512 + lane*8;
#pragma unroll
    for (int e=0;e<8;++e){
      o1[e]=f2bf(U1[(size_t)(k0+e)*NG+col]);
      o2[e]=f2bf(U2[(size_t)(k0+e)*NG+col]);
    }
  } else if (i < 49152) {                // W1 frags, 256
    int j=i-32768, lane=j&63, fi=j>>6;
    int nt=fi&15, w=(fi>>4)&3, kt=fi>>6;
    int col = w*256 + nt*16 + (lane&15);
    int k0  = kt*32 + (lane>>4)*8;
    u16* o = W1p + (size_t)fi*512 + lane*8;
#pragma unroll
    for (int e=0;e<8;++e) o[e]=f2bf(W1[(size_t)(k0+e)*NG+col]);
  } else if (i < 81920) {                // W2 frags, 512
    int j=i-49152, lane=j&63, fi=j>>6;
    int nt=fi&7, w=(fi>>3)&3, kt=(fi>>5)&7, p=fi>>8;
    int col = p*512 + w*128 + nt*16 + (lane&15);
    int k0  = kt*32 + (lane>>4)*8;
    u16* o = W2p + (size_t)fi*512 + lane*8;
#pragma unroll
    for (int e=0;e<8;++e) o[e]=f2bf(W2[(size_t)(k0+e)*NG+col]);
  }
}

// ---------------------------------------------------------------------------
// prep_init: sentinel-fill rings (f32 0xFFFFFFFF) + hring (bf16 0xFFFF);
// zero flags. Runs every launch -> erases replay staleness.
// ---------------------------------------------------------------------------
__global__ void prep_init(u64* ring1, u64* ring2, u64* hring, u32* flags){
  long i = (long)blockIdx.x*256 + threadIdx.x;      // 524288 threads
  for (long k=i; k<2097152; k+=524288){ a_st64(ring1+k,SENT64); a_st64(ring2+k,SENT64); }
  if (i < 262144) a_st64(hring+i, SENT64);
  if (i < FLAGS_N) flags[i] = 0;
}

// ---------------------------------------------------------------------------
// rec_scan: single-CU full-U recurrence for one layer-group (16 batch rows).
// 256 thr = 4 waves (1/SIMD, 512 arch regs). Wave w owns unit-cols
// w*64..+64 of ALL 4 gates -> pointwise is lane-local (zero exchange).
// U residency: kt 0..4 regs (pinned), kt 5..6 LDS (128 KiB), kt 7 streamed.
// h: LDS parity buffers, XOR-swizzled (row&7)<<4. acc preacts = ring[t]
// (x@W+b from producers, f32 sentinel) + h_{t-1}@U MFMAs.
// ---------------------------------------------------------------------------
template<bool IS1>
__device__ __forceinline__ void rec_scan(
    const u16* __restrict__ Upk, u32* ring, u64* hring,
    u32* flags, float* hlast, int g, char* lds)
{
  const int tid=threadIdx.x, lane=tid&63, w=tid>>6;
  const int l15=lane&15, l16=lane>>4;

  bf16x8 ufr[5][4][4];
#pragma unroll
  for (int kt=0;kt<5;++kt)
#pragma unroll
    for (int gg=0;gg<4;++gg)
#pragma unroll
      for (int ct=0;ct<4;++ct){
        int fi=((kt*4+w)*4+gg)*4+ct;
        ufr[kt][gg][ct]=*reinterpret_cast<const bf16x8*>(Upk+(size_t)fi*512+lane*8);
      }
#pragma unroll
  for (int kt=0;kt<5;++kt)
#pragma unroll
    for (int gg=0;gg<4;++gg)
#pragma unroll
      for (int ct=0;ct<4;++ct)
        asm volatile("" : "+v"(ufr[kt][gg][ct]));

  // LDS copy of kt 5..6 frag region (frag-linear both sides -> linear memcpy)
  {
    const uint4* src=reinterpret_cast<const uint4*>(Upk+(size_t)320*512);
    uint4* dst=reinterpret_cast<uint4*>(lds);
#pragma unroll
    for (int i2=0;i2<32;++i2) dst[tid+i2*256]=src[tid+i2*256];
  }
  __syncthreads();

  u32* prog  = flags + (IS1?F_PROG1(g):F_PROG2(g));
  u32* hwipe = flags + F_HWIPE(g);
  const size_t rB=(size_t)g*D*16*1024;     // ring base, u32 units
  const size_t hB=(size_t)g*D*16*64;       // hring base, u64 units
  long budget=50000000;
  float cst[4][4]={};

  for (int t=0;t<NT;++t){
    const int s=t&(D-1), par=t&1;

    // ---- L1: publish h_{t-1} (stable since last barrier) to hring ----
    if (IS1 && t>0){
      const int sp=(t-1)&(D-1);
      if (t-1>=D){
        u32 need=(u32)(t-D);                       // = (t-1)-D+1
        while (a_ld32(hwipe)<need){ if(--budget<=0) break; }
        asm volatile("":::"memory");
      }
      int row=tid>>4, ub0=(tid&15)*32, sw=(row&7)<<4;
      const char* hp=lds+131072+(par^1)*8192+row*512;
      uint4 q0=*reinterpret_cast<const uint4*>(hp+(ub0^sw));
      uint4 q1=*reinterpret_cast<const uint4*>(hp+((ub0+16)^sw));
      u64* go=hring+hB+((size_t)sp*16+row)*64+(tid&15)*4;
      a_st64(go+0,((u64)q0.y<<32)|q0.x);
      a_st64(go+1,((u64)q0.w<<32)|q0.z);
      a_st64(go+2,((u64)q1.y<<32)|q1.x);
      a_st64(go+3,((u64)q1.w<<32)|q1.z);
    }

    // ---- main phase: acc = ring[t] (staged per-gg) + h@U ----
    f32x4 acc[4][4];
#pragma unroll
    for (int gg=0;gg<4;++gg)
#pragma unroll
      for (int ct=0;ct<4;++ct) acc[gg][ct]=f32x4{0.f,0.f,0.f,0.f};

    float rv[2][16]; bf16x8 sf[2][4];
#pragma unroll
    for (int ct=0;ct<4;++ct){            // stage gg=0
      int col=w*64+ct*16+l15;
#pragma unroll
      for (int r=0;r<4;++r)
        rv[0][ct*4+r]=__uint_as_float(a_ld32(ring+rB+((size_t)s*16+(l16*4+r))*1024+col));
      int fi=((7*4+w)*4+0)*4+ct;
      sf[0][ct]=*reinterpret_cast<const bf16x8*>(Upk+(size_t)fi*512+lane*8);
    }

#pragma unroll
    for (int gg=0;gg<4;++gg){
      if (gg<3){                         // stage gg+1 (latency hidden by MFMAs)
        const int gn=gg+1, pb=gn&1;
#pragma unroll
        for (int ct=0;ct<4;++ct){
          int col=gn*256+w*64+ct*16+l15;
#pragma unroll
          for (int r=0;r<4;++r)
            rv[pb][ct*4+r]=__uint_as_float(a_ld32(ring+rB+((size_t)s*16+(l16*4+r))*1024+col));
          int fi=((7*4+w)*4+gn)*4+ct;
          sf[pb][ct]=*reinterpret_cast<const bf16x8*>(Upk+(size_t)fi*512+lane*8);
        }
      }
      if (t>0){
#pragma unroll
        for (int kt=0;kt<8;++kt){
          int ub=kt*64+l16*16;
          bf16x8 af=*reinterpret_cast<const bf16x8*>(
              lds+131072+(par^1)*8192+l15*512+(ub^((l15&7)<<4)));
#pragma unroll
          for (int ct=0;ct<4;++ct){
            bf16x8 bf;
            if (kt<5)      bf=ufr[kt][gg][ct];
            else if (kt<7) bf=*reinterpret_cast<const bf16x8*>(
                               lds+((((kt-5)*4+w)*4+gg)*4+ct)*1024+lane*16);
            else           bf=sf[gg&1][ct];
            acc[gg][ct]=mm(af,bf,acc[gg][ct]);
          }
        }
      }
      // sentinel check; add preacts into acc
      {
        bool ok=true;
#pragma unroll
        for (int i2=0;i2<16;++i2) ok=ok&&(__float_as_uint(rv[gg&1][i2])!=SENTF);
        if (!__all(ok?1:0)){
          for(;;){
            ok=true;
#pragma unroll
            for (int ct=0;ct<4;++ct){
              int col=gg*256+w*64+ct*16+l15;
#pragma unroll
              for (int r=0;r<4;++r){
                rv[gg&1][ct*4+r]=__uint_as_float(
                    a_ld32(ring+rB+((size_t)s*16+(l16*4+r))*1024+col));
                ok=ok&&(__float_as_uint(rv[gg&1][ct*4+r])!=SENTF);
              }
            }
            if (__all(ok?1:0)) break;
            if (--budget<=0) break;
          }
          asm volatile("":::"memory");
        }
#pragma unroll
        for (int ct=0;ct<4;++ct)
#pragma unroll
          for (int r=0;r<4;++r) acc[gg][ct][r]+=rv[gg&1][ct*4+r];
      }
    }

    // ---- pointwise (all 4 gates lane-local; Keras order i,f,cbar,o) ----
    u16 hh[16];
#pragma unroll
    for (int ct=0;ct<4;++ct)
#pragma unroll
      for (int r=0;r<4;++r){
        float iv=sigm(acc[0][ct][r]);
        float fv=sigm(acc[1][ct][r]);
        float cd=tanh_(acc[2][ct][r]);
        float ov=sigm(acc[3][ct][r]);
        cst[ct][r]=fv*cst[ct][r]+iv*cd;
        float hv=ov*tanh_(cst[ct][r]);
        hh[ct*4+r]=f2bf(hv);
        if (!IS1 && t==NT-1)
          hlast[(size_t)(g*16+l16*4+r)*NH + w*64+ct*16+l15]=hv;
      }
#pragma unroll
    for (int ct=0;ct<4;++ct)
#pragma unroll
      for (int r=0;r<4;++r){
        int row=l16*4+r, ub=(w*64+ct*16+l15)*2;
        *reinterpret_cast<u16*>(lds+131072+par*8192+row*512+(ub^((row&7)<<4)))=hh[ct*4+r];
      }
    __syncthreads();   // h_t complete; all ring[t] loads done (enables wipe)

    // ---- batched ring wipe + progress (every 8 steps) ----
    if ((t&7)==7){
      for (int ss=t-7;ss<=t;++ss){
        u64* wp=reinterpret_cast<u64*>(ring)+((size_t)g*D+(ss&(D-1)))*8192;
#pragma unroll
        for (int i2=0;i2<32;++i2) a_st64(wp+tid+i2*256,SENT64);
      }
      vmw();
      if (tid==0) a_st32(prog,(u32)(t+1));
    }
  }

  if (IS1){   // publish final h_{NT-1} (feeds xw2 -> ring2 -> L2's last step)
    const int sp=(NT-1)&(D-1);
    u32 need=(u32)(NT-1-D+1);
    while (a_ld32(hwipe)<need){ if(--budget<=0) break; }
    asm volatile("":::"memory");
    int row=tid>>4, ub0=(tid&15)*32, sw=(row&7)<<4;
    const char* hp=lds+131072+((NT-1)&1)*8192+row*512;
    uint4 q0=*reinterpret_cast<const uint4*>(hp+(ub0^sw));
    uint4 q1=*reinterpret_cast<const uint4*>(hp+((ub0+16)^sw));
    u64* go=hring+hB+((size_t)sp*16+row)*64+(tid&15)*4;
    a_st64(go+0,((u64)q0.y<<32)|q0.x);
    a_st64(go+1,((u64)q0.w<<32)|q0.z);
    a_st64(go+2,((u64)q1.y<<32)|q1.x);
    a_st64(go+3,((u64)q1.w<<32)|q1.z);
  }
}

// ---------------------------------------------------------------------------
// xw1_prod: ring1[g][t%D] = x[g-rows,t]@W1 + b1 (f32). No deps; back-pressure
// on prog1. Fire-and-forget stores (sentinel protocol).
// ---------------------------------------------------------------------------
__device__ __forceinline__ void xw1_prod(
    const float* __restrict__ x, const u16* __restrict__ Wpk,
    const float* __restrict__ b1, u32* ring, u32* flags, int g)
{
  const int tid=threadIdx.x, lane=tid&63, w=tid>>6;
  const int l15=lane&15, l16=lane>>4;
  bf16x8 wfr[4][16];
#pragma unroll
  for (int kt=0;kt<4;++kt)
#pragma unroll
    for (int nt=0;nt<16;++nt){
      int fi=(kt*4+w)*16+nt;
      wfr[kt][nt]=*reinterpret_cast<const bf16x8*>(Wpk+(size_t)fi*512+lane*8);
    }
#pragma unroll
  for (int kt=0;kt<4;++kt)
#pragma unroll
    for (int nt=0;nt<16;++nt) asm volatile("" : "+v"(wfr[kt][nt]));
  float bb[16];
#pragma unroll
  for (int nt=0;nt<16;++nt) bb[nt]=b1[w*256+nt*16+l15];

  u32* prog=flags+F_PROG1(g);
  const size_t rB=(size_t)g*D*16*1024;
  const long xrow=(long)(g*16+l15)*NT;
  long budget=50000000;

  for (int t=0;t<NT;++t){
    if (t>=D){
      u32 need=(u32)(t-D+1);
      while (a_ld32(prog)<need){ if(--budget<=0) break; }
      asm volatile("":::"memory");
    }
    bf16x8 ax[4];
    const float* xp0=x+(xrow+t)*NF;
#pragma unroll
    for (int kt=0;kt<4;++kt){
      f32x4 x0=*reinterpret_cast<const f32x4*>(xp0+kt*32+l16*8);
      f32x4 x1=*reinterpret_cast<const f32x4*>(xp0+kt*32+l16*8+4);
      union{u16 s2[8];bf16x8 v;}cv;
#pragma unroll
      for (int e=0;e<4;++e){cv.s2[e]=f2bf(x0[e]);cv.s2[4+e]=f2bf(x1[e]);}
      ax[kt]=cv.v;
    }
    f32x4 acc[16];
#pragma unroll
    for (int nt=0;nt<16;++nt) acc[nt]=f32x4{bb[nt],bb[nt],bb[nt],bb[nt]};
#pragma unroll
    for (int kt=0;kt<4;++kt)
#pragma unroll
      for (int nt=0;nt<16;++nt) acc[nt]=mm(ax[kt],wfr[kt][nt],acc[nt]);
    const int s=t&(D-1);
#pragma unroll
    for (int nt=0;nt<16;++nt){
      int col=w*256+nt*16+l15;
#pragma unroll
      for (int r=0;r<4;++r)
        a_st32(ring+rB+((size_t)s*16+(l16*4+r))*1024+col,__float_as_uint(acc[nt][r]));
    }
  }
}

// ---------------------------------------------------------------------------
// xw2_prod: ring2[g][t%D][:, p-half] = hring[g][t]@W2 + b2. Consumes hring
// via R9 sentinel; p=0 wipes hring slots once BOTH halves consumed (cp gate)
// and publishes hwipe (gates L1's publish). Back-pressure on prog2.
// ---------------------------------------------------------------------------
__device__ __forceinline__ void xw2_prod(
    const u16* __restrict__ Wpk, const float* __restrict__ b2,
    u64* hring, u32* ring2, u32* flags, int g, int p)
{
  const int tid=threadIdx.x, lane=tid&63, w=tid>>6;
  const int l15=lane&15, l16=lane>>4;
  bf16x8 wfr[8][8];
#pragma unroll
  for (int kt=0;kt<8;++kt)
#pragma unroll
    for (int nt=0;nt<8;++nt){
      int fi=((p*8+kt)*4+w)*8+nt;
      wfr[kt][nt]=*reinterpret_cast<const bf16x8*>(Wpk+(size_t)fi*512+lane*8);
    }
#pragma unroll
  for (int kt=0;kt<8;++kt)
#pragma unroll
    for (int nt=0;nt<8;++nt) asm volatile("" : "+v"(wfr[kt][nt]));
  float bb[8];
#pragma unroll
  for (int nt=0;nt<8;++nt) bb[nt]=b2[p*512+w*128+nt*16+l15];

  u32* prog2=flags+F_PROG2(g);
  u32* mycp =flags+F_CP(g,p);
  u32* otcp =flags+F_CP(g,1-p);
  u32* hwipe=flags+F_HWIPE(g);
  const size_t rB=(size_t)g*D*16*1024;
  const size_t hB=(size_t)g*D*16*64;
  long budget=50000000;
  u32 wiped=0;

  for (int t=0;t<NT;++t){
    if (t>=D){
      u32 need=(u32)(t-D+1);
      while (a_ld32(prog2)<need){ if(--budget<=0) break; }
      asm volatile("":::"memory");
    }
    const int s=t&(D-1);
    u64 hr[8][2];
    const u64* hb=hring+hB+((size_t)s*16+l15)*64;
    for(;;){
      bool ok=true;
#pragma unroll
      for (int kt=0;kt<8;++kt){
        hr[kt][0]=a_ld64(hb+kt*8+l16*2);
        hr[kt][1]=a_ld64(hb+kt*8+l16*2+1);
      }
#pragma unroll
      for (int kt=0;kt<8;++kt) ok=ok&&(hr[kt][0]!=SENT64)&&(hr[kt][1]!=SENT64);
      if (__all(ok?1:0)) break;
      if (--budget<=0) break;
    }
    asm volatile("":::"memory");
    f32x4 acc[8];
#pragma unroll
    for (int nt=0;nt<8;++nt) acc[nt]=f32x4{bb[nt],bb[nt],bb[nt],bb[nt]};
#pragma unroll
    for (int kt=0;kt<8;++kt){
      union{u64 q[2];bf16x8 v;}cv; cv.q[0]=hr[kt][0]; cv.q[1]=hr[kt][1];
#pragma unroll
      for (int nt=0;nt<8;++nt) acc[nt]=mm(cv.v,wfr[kt][nt],acc[nt]);
    }
#pragma unroll
    for (int nt=0;nt<8;++nt){
      int col=p*512+w*128+nt*16+l15;
#pragma unroll
      for (int r=0;r<4;++r)
        a_st32(ring2+rB+((size_t)s*16+(l16*4+r))*1024+col,__float_as_uint(acc[nt][r]));
    }
    if ((t&7)==7){
      __syncthreads();                       // whole WG consumed through t
      if (tid==0) a_st32(mycp,(u32)(t+1));
      if (p==0){
        u32 oc=a_ld32(otcp);
        u32 lim=oc<(u32)(t+1)?oc:(u32)(t+1);
        if (wiped<lim){
          for (u32 ss=wiped;ss<lim;++ss){
            u64* wp=hring+hB+(size_t)(ss&(D-1))*1024;
#pragma unroll
            for (int i2=0;i2<4;++i2) a_st64(wp+tid+i2*256,SENT64);
          }
          vmw();
          if (tid==0) a_st32(hwipe,lim);
          wiped=lim;
        }
      }
    }
  }
}

// ---------------------------------------------------------------------------
__global__ __launch_bounds__(256,1) void lstm_all(
    const float* __restrict__ x,
    const u16* __restrict__ U1p, const u16* __restrict__ U2p,
    const u16* __restrict__ W1p, const u16* __restrict__ W2p,
    const float* __restrict__ b1, const float* __restrict__ b2,
    u32* ring1, u32* ring2, u64* hring, float* hlast, u32* flags)
{
  __shared__ __align__(16) char lds[147456];   // 128K U(kt5,6) + 2x8K h parity
  const int bid=blockIdx.x;
  if      (bid<8)  rec_scan<true >(U1p, ring1, hring, flags, nullptr, bid,    lds);
  else if (bid<16) rec_scan<false>(U2p, ring2, hring, flags, hlast,   bid-8,  lds);
  else if (bid<24) xw1_prod(x, W1p, b1, ring1, flags, bid-16);
  else             xw2_prod(W2p, b2, hring, ring2, flags, (bid-24)>>1, (bid-24)&1);
}

// ---------------------------------------------------------------------------
__global__ void dense_out(const float* __restrict__ hl, const float* __restrict__ Wd,
                          const float* __restrict__ bd, float* __restrict__ out) {
  int b = blockIdx.x, l = threadIdx.x;
  f32x4 h  = *reinterpret_cast<const f32x4*>(hl + (long)b * NH + l * 4);
  f32x4 wv = *reinterpret_cast<const f32x4*>(Wd + l * 4);
  float s = h[0]*wv[0] + h[1]*wv[1] + h[2]*wv[2] + h[3]*wv[3];
#pragma unroll
  for (int off = 32; off > 0; off >>= 1) s += __shfl_down(s, off);
  if (l == 0) out[b] = fmaxf(s + bd[0], 0.f);
}

// ---------------------------------------------------------------------------
extern "C" void kernel_launch(void* const* d_in, const int* in_sizes, int n_in,
                              void* d_out, int out_size, void* d_ws, size_t ws_size,
                              hipStream_t stream) {
  const float* x  = (const float*)d_in[0];
  const float* W1 = (const float*)d_in[1];
  const float* U1 = (const float*)d_in[2];
  const float* b1 = (const float*)d_in[3];
  const float* W2 = (const float*)d_in[4];
  const float* U2 = (const float*)d_in[5];
  const float* b2 = (const float*)d_in[6];
  const float* Wd = (const float*)d_in[7];
  const float* bd = (const float*)d_in[8];
  float* out = (float*)d_out;

  char* ws = (char*)d_ws;
  size_t off = 0;
  auto alloc = [&](size_t bytes) -> char* {
    char* p = ws + off;
    off = (off + bytes + 255) & ~(size_t)255;
    return p;
  };
  u16* U1p   = (u16*)alloc(512u*1024);                       // 512 KiB
  u16* U2p   = (u16*)alloc(512u*1024);
  u16* W1p   = (u16*)alloc(256u*1024);
  u16* W2p   = (u16*)alloc(512u*1024);
  u32* ring1 = (u32*)alloc((size_t)8*D*16*1024*4);           // 16 MiB
  u32* ring2 = (u32*)alloc((size_t)8*D*16*1024*4);           // 16 MiB
  u64* hring = (u64*)alloc((size_t)8*D*16*64*8);             // 2 MiB
  float* hlast = (float*)alloc((size_t)NB*NH*4);             // 128 KiB
  u32* flags = (u32*)alloc(FLAGS_N*4);

  if (off > ws_size) {
    // workspace too small: finite sentinel 0x42424242 ~= 48.56 (NOT NaN)
    hipMemsetAsync(d_out, 0x42, (size_t)out_size * sizeof(float), stream);
    return;
  }

  prep_pack<<<320, 256, 0, stream>>>(U1, U2, W1, W2, U1p, U2p, W1p, W2p);
  prep_init<<<2048, 256, 0, stream>>>((u64*)ring1, (u64*)ring2, hring, flags);
  lstm_all<<<40, 256, 0, stream>>>(x, U1p, U2p, W1p, W2p, b1, b2,
                                   ring1, ring2, hring, hlast, flags);
  dense_out<<<128, 64, 0, stream>>>(hlast, Wd, bd, out);
}

// Round 13
// 12431.329 us; speedup vs baseline: 1.1613x; 1.1613x over previous
//
#include <hip/hip_runtime.h>

typedef __bf16 bf16x8 __attribute__((ext_vector_type(8)));
typedef float  f32x4  __attribute__((ext_vector_type(4)));
typedef unsigned short u16;
typedef unsigned int   u32;
typedef unsigned long long u64;

#define NB 128
#define NT 1024
#define NF 128
#define NH 256
#define NG 1024
#define D  32                  // preact ring depth (steps)
#define HD 64                  // hring depth (steps)
#define SENT64 (~0ull)

// flags (u32 offsets, 64B-padded)
#define F_PW1(g)   ((g)*16)          // xw1 produce progress (ring1)
#define F_C1(g)    (128+(g)*16)      // L1 rec consume progress (ring1)
#define F_PW2A(g)  (256+(g)*16)      // xw2 p=0 produce progress (ring2)
#define F_PW2B(g)  (384+(g)*16)      // xw2 p=1 produce progress
#define F_C2(g)    (512+(g)*16)      // L2 rec consume progress (ring2)
#define F_CPA(g)   (640+(g)*16)      // xw2 p=0 hring consume progress
#define F_CPB(g)   (768+(g)*16)      // xw2 p=1 hring consume progress
#define F_HWIPE(g) (896+(g)*16)      // hring wiped-through count
#define FLAGS_N 1024

__device__ __forceinline__ u16 f2bf(float f){ union{float f;u32 u;}c;c.f=f;u32 u=c.u;return (u16)((u+0x7fffu+((u>>16)&1u))>>16);}
__device__ __forceinline__ float sigm(float x){return 1.f/(1.f+__expf(-x));}
__device__ __forceinline__ float tanh_(float x){return 1.f-2.f/(1.f+__expf(2.f*x));}
__device__ __forceinline__ f32x4 mm(bf16x8 a,bf16x8 b,f32x4 c){return __builtin_amdgcn_mfma_f32_16x16x32_bf16(a,b,c,0,0,0);}
__device__ __forceinline__ u32 a_ld32(const u32*p){return __hip_atomic_load((u32*)p,__ATOMIC_RELAXED,__HIP_MEMORY_SCOPE_AGENT);}
__device__ __forceinline__ u64 a_ld64(const u64*p){return __hip_atomic_load((u64*)p,__ATOMIC_RELAXED,__HIP_MEMORY_SCOPE_AGENT);}
__device__ __forceinline__ void a_st32(u32*p,u32 v){__hip_atomic_store(p,v,__ATOMIC_RELAXED,__HIP_MEMORY_SCOPE_AGENT);}
__device__ __forceinline__ void a_st64(u64*p,u64 v){__hip_atomic_store(p,v,__ATOMIC_RELAXED,__HIP_MEMORY_SCOPE_AGENT);}
__device__ __forceinline__ void vmw(){asm volatile("s_waitcnt vmcnt(0)":::"memory");}

// ---------------------------------------------------------------------------
// prep_pack (R12-verbatim, verified): weights fp32 -> bf16 frag-linear packs.
// ---------------------------------------------------------------------------
__global__ void prep_pack(const float* __restrict__ U1,const float* __restrict__ U2,
                          const float* __restrict__ W1,const float* __restrict__ W2,
                          u16* __restrict__ U1p,u16* __restrict__ U2p,
                          u16* __restrict__ W1p,u16* __restrict__ W2p){
  int i = blockIdx.x*256+threadIdx.x;
  if (i < 32768) {
    int lane=i&63, fi=i>>6;
    int ct=fi&3, gg=(fi>>2)&3, w=(fi>>4)&3, kt=fi>>6;
    int col = gg*256 + w*64 + ct*16 + (lane&15);
    int k0  = kt*32 + (lane>>4)*8;
    u16* o1 = U1p + (size_t)fi*512 + lane*8;
    u16* o2 = U2p + (size_t)fi*512 + lane*8;
#pragma unroll
    for (int e=0;e<8;++e){
      o1[e]=f2bf(U1[(size_t)(k0+e)*NG+col]);
      o2[e]=f2bf(U2[(size_t)(k0+e)*NG+col]);
    }
  } else if (i < 49152) {
    int j=i-32768, lane=j&63, fi=j>>6;
    int nt=fi&15, w=(fi>>4)&3, kt=fi>>6;
    int col = w*256 + nt*16 + (lane&15);
    int k0  = kt*32 + (lane>>4)*8;
    u16* o = W1p + (size_t)fi*512 + lane*8;
#pragma unroll
    for (int e=0;e<8;++e) o[e]=f2bf(W1[(size_t)(k0+e)*NG+col]);
  } else if (i < 81920) {
    int j=i-49152, lane=j&63, fi=j>>6;
    int nt=fi&7, w=(fi>>3)&3, kt=(fi>>5)&7, p=fi>>8;
    int col = p*512 + w*128 + nt*16 + (lane&15);
    int k0  = kt*32 + (lane>>4)*8;
    u16* o = W2p + (size_t)fi*512 + lane*8;
#pragma unroll
    for (int e=0;e<8;++e) o[e]=f2bf(W2[(size_t)(k0+e)*NG+col]);
  }
}

// ---------------------------------------------------------------------------
__global__ void prep_init(u64* hring, u32* flags){
  long i = (long)blockIdx.x*256 + threadIdx.x;     // 524288 threads
  if (i < 8L*HD*1024) a_st64(hring+i, SENT64);
  if (i < FLAGS_N) flags[i] = 0;
}

// ---------------------------------------------------------------------------
// rec_scan: single-CU recurrence. U: kt0..3 pinned regs, kt4..5 LDS, kt6..7
// streamed (L2-resident). h: LDS parity, XOR-swizzled. Preacts: prefetched
// one step ahead from the counter-gated ring (consumer-major layout).
// ---------------------------------------------------------------------------
template<bool IS1>
__device__ __forceinline__ void rec_scan(
    const u16* __restrict__ Upk, u64* __restrict__ ring, u64* __restrict__ hring,
    u32* __restrict__ flags, float* __restrict__ hlast, int g, char* lds)
{
  const int tid=threadIdx.x, lane=tid&63, w=tid>>6;
  const int l15=lane&15, l16=lane>>4;

  bf16x8 ufr[4][4][4];
#pragma unroll
  for (int kt=0;kt<4;++kt)
#pragma unroll
    for (int gg=0;gg<4;++gg)
#pragma unroll
      for (int ct=0;ct<4;++ct)
        ufr[kt][gg][ct]=*reinterpret_cast<const bf16x8*>(
            Upk+(size_t)((((kt*4+w)*4+gg)*4)+ct)*512+lane*8);
#pragma unroll
  for (int kt=0;kt<4;++kt)
#pragma unroll
    for (int gg=0;gg<4;++gg)
#pragma unroll
      for (int ct=0;ct<4;++ct)
        asm volatile("" : "+v"(ufr[kt][gg][ct]));

  { // LDS copy of kt4..5 frag region (fi 256..383), 128 KiB
    const uint4* src=reinterpret_cast<const uint4*>(Upk+(size_t)256*512);
    uint4* dst=reinterpret_cast<uint4*>(lds);
#pragma unroll
    for (int i2=0;i2<32;++i2) dst[tid+i2*256]=src[tid+i2*256];
  }
  __syncthreads();

  u32* progA = flags + (IS1?F_PW1(g):F_PW2A(g));
  u32* progB = flags + F_PW2B(g);
  u32* cons  = flags + (IS1?F_C1(g):F_C2(g));
  u32* hwipe = flags + F_HWIPE(g);
  const size_t rB=(size_t)(g*D)*8192;     // ring u64 base
  const size_t hB=(size_t)(g*HD)*1024;    // hring u64 base
  long budget=4000000;
  float cst[4][4]={};
  u32 avail=0, hwv=0;

  u64 pr[32];
  { // preload slot 0
    while (avail<1u){
      u32 a=a_ld32(progA);
      if (!IS1){ u32 b2=a_ld32(progB); a=a<b2?a:b2; }
      avail=a; if (avail>=1u) break; if(--budget<=0) break;
    }
    asm volatile("":::"memory");
#pragma unroll
    for (int i2=0;i2<32;++i2) pr[i2]=a_ld64(ring+rB+(size_t)i2*256+tid);
  }

  for (int t=0;t<NT;++t){
    const int par=t&1;

    // publish h_{t-1} -> hring (fire-and-forget; rare hwipe gate)
    if (IS1 && t>0){
      if (t>HD){
        u32 need=(u32)(t-HD);
        while (hwv<need){ hwv=a_ld32(hwipe); if (hwv>=need) break; if(--budget<=0) break; }
        asm volatile("":::"memory");
      }
      const int sp=(t-1)&(HD-1);
      int row=tid>>4, ub0=(tid&15)*32, sw=(row&7)<<4;
      const char* hp=lds+131072+(par^1)*8192+row*512;
      uint4 q0=*reinterpret_cast<const uint4*>(hp+(ub0^sw));
      uint4 q1=*reinterpret_cast<const uint4*>(hp+((ub0+16)^sw));
      u64* go=hring+hB+((size_t)sp*16+row)*64+(tid&15)*4;
      a_st64(go+0,((u64)q0.y<<32)|q0.x);
      a_st64(go+1,((u64)q0.w<<32)|q0.z);
      a_st64(go+2,((u64)q1.y<<32)|q1.x);
      a_st64(go+3,((u64)q1.w<<32)|q1.z);
    }

    float ia[16], fa[16], ca[16], hv[16];
#pragma unroll
    for (int gg=0;gg<4;++gg){
      // streamed frags kt6,7 (L2-resident constant)
      bf16x8 s6[4], s7[4];
#pragma unroll
      for (int ct=0;ct<4;++ct){
        s6[ct]=*reinterpret_cast<const bf16x8*>(Upk+(size_t)(((6*4+w)*4+gg)*4+ct)*512+lane*8);
        s7[ct]=*reinterpret_cast<const bf16x8*>(Upk+(size_t)(((7*4+w)*4+gg)*4+ct)*512+lane*8);
      }
      f32x4 acc[4]={};
      if (t>0){
#pragma unroll
        for (int kt=0;kt<8;++kt){
          const int ub=kt*64+l16*16;
          bf16x8 af=*reinterpret_cast<const bf16x8*>(
              lds+131072+(par^1)*8192+l15*512+(ub^((l15&7)<<4)));
#pragma unroll
          for (int ct=0;ct<4;++ct){
            bf16x8 bfv;
            if (kt<4)      bfv=ufr[kt][gg][ct];
            else if (kt<6) bfv=*reinterpret_cast<const bf16x8*>(
                lds+(size_t)((((kt-4)*4+w)*4+gg)*4+ct)*1024+lane*16);
            else           bfv=(kt==6)?s6[ct]:s7[ct];
            acc[ct]=mm(af,bfv,acc[ct]);
          }
        }
      }
      // consume preacts + activate this gate
#pragma unroll
      for (int ct=0;ct<4;++ct)
#pragma unroll
        for (int rr=0;rr<2;++rr){
          const u64 q=pr[gg*8+ct*2+rr];
          const int i0=ct*4+rr*2;
          float v0=__uint_as_float((u32)q)       +acc[ct][rr*2];
          float v1=__uint_as_float((u32)(q>>32)) +acc[ct][rr*2+1];
          if      (gg==0){ ia[i0]=sigm(v0);  ia[i0+1]=sigm(v1); }
          else if (gg==1){ fa[i0]=sigm(v0);  fa[i0+1]=sigm(v1); }
          else if (gg==2){ ca[i0]=tanh_(v0); ca[i0+1]=tanh_(v1); }
          else {
            float o0=sigm(v0), o1=sigm(v1);
            cst[ct][rr*2]  =fa[i0]  *cst[ct][rr*2]  +ia[i0]  *ca[i0];
            cst[ct][rr*2+1]=fa[i0+1]*cst[ct][rr*2+1]+ia[i0+1]*ca[i0+1];
            hv[i0]  =o0*tanh_(cst[ct][rr*2]);
            hv[i0+1]=o1*tanh_(cst[ct][rr*2+1]);
          }
        }
      // prefetch this gg-chunk for step t+1 (producers run ~D ahead)
      if (t+1<NT){
        if (gg==0){
          const u32 need=(u32)(t+2);
          while (avail<need){
            u32 a=a_ld32(progA);
            if (!IS1){ u32 b2=a_ld32(progB); a=a<b2?a:b2; }
            avail=a; if (avail>=need) break; if(--budget<=0) break;
          }
          asm volatile("":::"memory");
        }
        const size_t nb=rB+(size_t)((t+1)&(D-1))*8192;
#pragma unroll
        for (int k2=0;k2<8;++k2) pr[gg*8+k2]=a_ld64(ring+nb+(size_t)(gg*8+k2)*256+tid);
      }
    }

    // h_t -> LDS parity (swizzled); hlast at the end (L2)
#pragma unroll
    for (int ct=0;ct<4;++ct)
#pragma unroll
      for (int r=0;r<4;++r){
        const int row=l16*4+r, ub=(w*64+ct*16+l15)*2;
        *reinterpret_cast<u16*>(lds+131072+par*8192+row*512+(ub^((row&7)<<4)))
            =f2bf(hv[ct*4+r]);
        if (!IS1 && t==NT-1)
          hlast[(size_t)(g*16+l16*4+r)*NH + w*64+ct*16+l15]=hv[ct*4+r];
      }
    __syncthreads();
    if ((t&7)==7 && tid==0) a_st32(cons,(u32)(t+1));
  }

  if (IS1){ // final h_{NT-1}
    u32 need=(u32)(NT-HD);
    while (hwv<need){ hwv=a_ld32(hwipe); if (hwv>=need) break; if(--budget<=0) break; }
    asm volatile("":::"memory");
    const int sp=(NT-1)&(HD-1);
    int row=tid>>4, ub0=(tid&15)*32, sw=(row&7)<<4;
    const char* hp=lds+131072+((NT-1)&1)*8192+row*512;
    uint4 q0=*reinterpret_cast<const uint4*>(hp+(ub0^sw));
    uint4 q1=*reinterpret_cast<const uint4*>(hp+((ub0+16)^sw));
    u64* go=hring+hB+((size_t)sp*16+row)*64+(tid&15)*4;
    a_st64(go+0,((u64)q0.y<<32)|q0.x);
    a_st64(go+1,((u64)q0.w<<32)|q0.z);
    a_st64(go+2,((u64)q1.y<<32)|q1.x);
    a_st64(go+3,((u64)q1.w<<32)|q1.z);
  }
}

// ---------------------------------------------------------------------------
// xw1_prod: ring1[t] = x@W1 + b1 (consumer-major layout, counter-gated).
// ---------------------------------------------------------------------------
__device__ __forceinline__ void xw1_prod(
    const float* __restrict__ x, const u16* __restrict__ Wpk,
    const float* __restrict__ b1, u64* __restrict__ ring,
    u32* __restrict__ flags, int g)
{
  const int tid=threadIdx.x, lane=tid&63, w=tid>>6;
  const int l15=lane&15, l16=lane>>4;
  bf16x8 wfr[4][16];
#pragma unroll
  for (int kt=0;kt<4;++kt)
#pragma unroll
    for (int nt=0;nt<16;++nt)
      wfr[kt][nt]=*reinterpret_cast<const bf16x8*>(Wpk+(size_t)((kt*4+w)*16+nt)*512+lane*8);
#pragma unroll
  for (int kt=0;kt<4;++kt)
#pragma unroll
    for (int nt=0;nt<16;++nt) asm volatile("" : "+v"(wfr[kt][nt]));
  float bb[16];
#pragma unroll
  for (int nt=0;nt<16;++nt) bb[nt]=b1[w*256+nt*16+l15];

  u32* cons=flags+F_C1(g); u32* prog=flags+F_PW1(g);
  const size_t rB=(size_t)(g*D)*8192;
  const long xrow=(long)(g*16+l15)*NT;
  long budget=4000000; u32 consc=0;

  for (int t=0;t<NT;++t){
    if ((t&7)==0 && t+8>(int)D){
      u32 need=(u32)(t+8-D);
      while (consc<need){ consc=a_ld32(cons); if (consc>=need) break; if(--budget<=0) break; }
      asm volatile("":::"memory");
    }
    bf16x8 ax[4];
    const float* xp0=x+(xrow+t)*NF;
#pragma unroll
    for (int kt=0;kt<4;++kt){
      f32x4 x0=*reinterpret_cast<const f32x4*>(xp0+kt*32+l16*8);
      f32x4 x1=*reinterpret_cast<const f32x4*>(xp0+kt*32+l16*8+4);
      union{u16 s2[8];bf16x8 v;}cv;
#pragma unroll
      for (int e=0;e<4;++e){cv.s2[e]=f2bf(x0[e]);cv.s2[4+e]=f2bf(x1[e]);}
      ax[kt]=cv.v;
    }
    f32x4 acc[16];
#pragma unroll
    for (int nt=0;nt<16;++nt) acc[nt]=f32x4{bb[nt],bb[nt],bb[nt],bb[nt]};
#pragma unroll
    for (int kt=0;kt<4;++kt)
#pragma unroll
      for (int nt=0;nt<16;++nt) acc[nt]=mm(ax[kt],wfr[kt][nt],acc[nt]);
    const size_t sb=rB+(size_t)(t&(D-1))*8192;
#pragma unroll
    for (int nt=0;nt<16;++nt){
      const size_t tb=(size_t)(nt>>2)*64+lane;
#pragma unroll
      for (int rr=0;rr<2;++rr){
        u64 v=((u64)__float_as_uint(acc[nt][rr*2+1])<<32)|__float_as_uint(acc[nt][rr*2]);
        a_st64(ring+sb+(size_t)(w*8+(nt&3)*2+rr)*256+tb,v);
      }
    }
    if ((t&7)==7){ vmw(); __syncthreads(); if (tid==0) a_st32(prog,(u32)(t+1)); }
  }
}

// ---------------------------------------------------------------------------
// xw2_prod: ring2[t] half-p = hring[t]@W2 + b2. hring consumed via sentinel
// with one-slot prefetch; p=0 wipes consumed slots (uniform via LDS bcast).
// ---------------------------------------------------------------------------
__device__ __forceinline__ void xw2_prod(
    const u16* __restrict__ Wpk, const float* __restrict__ b2,
    u64* __restrict__ hring, u64* __restrict__ ring2,
    u32* __restrict__ flags, int g, int p, char* lds)
{
  const int tid=threadIdx.x, lane=tid&63, w=tid>>6;
  const int l15=lane&15, l16=lane>>4;
  bf16x8 wfr[8][8];
#pragma unroll
  for (int kt=0;kt<8;++kt)
#pragma unroll
    for (int nt=0;nt<8;++nt)
      wfr[kt][nt]=*reinterpret_cast<const bf16x8*>(Wpk+(size_t)(((p*8+kt)*4+w)*8+nt)*512+lane*8);
#pragma unroll
  for (int kt=0;kt<8;++kt)
#pragma unroll
    for (int nt=0;nt<8;++nt) asm volatile("" : "+v"(wfr[kt][nt]));
  float bb[8];
#pragma unroll
  for (int nt=0;nt<8;++nt) bb[nt]=b2[p*512+w*128+nt*16+l15];

  u32* prog = flags + (p? F_PW2B(g):F_PW2A(g));
  u32* cons = flags + F_C2(g);
  u32* mycp = flags + (p? F_CPB(g):F_CPA(g));
  u32* otcp = flags + (p? F_CPA(g):F_CPB(g));
  u32* hwipe= flags + F_HWIPE(g);
  const size_t rB=(size_t)(g*D)*8192;
  const size_t hB=(size_t)(g*HD)*1024;
  long budget=4000000; u32 consc=0, wiped=0;

  u64 hr[8][2];
  { // speculative preload of slot 0
    const u64* hb=hring+hB+(size_t)l15*64;
#pragma unroll
    for (int kt=0;kt<8;++kt){ hr[kt][0]=a_ld64(hb+kt*8+l16*2); hr[kt][1]=a_ld64(hb+kt*8+l16*2+1); }
  }

  for (int t=0;t<NT;++t){
    if ((t&7)==0 && t+8>(int)D){
      u32 need=(u32)(t+8-D);
      while (consc<need){ consc=a_ld32(cons); if (consc>=need) break; if(--budget<=0) break; }
      asm volatile("":::"memory");
    }
    const int s=t&(HD-1);
    const u64* hb=hring+hB+((size_t)s*16+l15)*64;
    { // sentinel check on prefetched data; re-poll on miss
      bool ok=true;
#pragma unroll
      for (int kt=0;kt<8;++kt) ok=ok&&(hr[kt][0]!=SENT64)&&(hr[kt][1]!=SENT64);
      while (!__all(ok?1:0)){
        if (--budget<=0) break;
#pragma unroll
        for (int kt=0;kt<8;++kt){ hr[kt][0]=a_ld64(hb+kt*8+l16*2); hr[kt][1]=a_ld64(hb+kt*8+l16*2+1); }
        ok=true;
#pragma unroll
        for (int kt=0;kt<8;++kt) ok=ok&&(hr[kt][0]!=SENT64)&&(hr[kt][1]!=SENT64);
      }
      asm volatile("":::"memory");
    }
    f32x4 acc[8];
#pragma unroll
    for (int nt=0;nt<8;++nt) acc[nt]=f32x4{bb[nt],bb[nt],bb[nt],bb[nt]};
#pragma unroll
    for (int kt=0;kt<8;++kt){
      union{u64 q[2];bf16x8 v;}cv; cv.q[0]=hr[kt][0]; cv.q[1]=hr[kt][1];
#pragma unroll
      for (int nt=0;nt<8;++nt) acc[nt]=mm(cv.v,wfr[kt][nt],acc[nt]);
    }
    // speculative prefetch of next slot
    if (t+1<NT){
      const u64* nhb=hring+hB+((size_t)((t+1)&(HD-1))*16+l15)*64;
#pragma unroll
      for (int kt=0;kt<8;++kt){ hr[kt][0]=a_ld64(nhb+kt*8+l16*2); hr[kt][1]=a_ld64(nhb+kt*8+l16*2+1); }
    }
    const size_t sb=rB+(size_t)(t&(D-1))*8192;
    const int ggb=p*2+(w>>1);
#pragma unroll
    for (int nt=0;nt<8;++nt){
      const size_t tb=(size_t)(((w&1)*2)+(nt>>2))*64+(l16*16+l15);
#pragma unroll
      for (int rr=0;rr<2;++rr){
        u64 v=((u64)__float_as_uint(acc[nt][rr*2+1])<<32)|__float_as_uint(acc[nt][rr*2]);
        a_st64(ring2+sb+(size_t)(ggb*8+(nt&3)*2+rr)*256+tb,v);
      }
    }
    if ((t&7)==7){
      vmw(); __syncthreads();
      if (tid==0){ a_st32(prog,(u32)(t+1)); a_st32(mycp,(u32)(t+1)); }
      if (p==0){
        volatile u32* sh=(volatile u32*)lds;
        if (tid==0){ u32 oc=a_ld32(otcp); u32 lim=oc<(u32)(t+1)?oc:(u32)(t+1); sh[0]=lim; }
        __syncthreads();
        u32 lim=sh[0];
        if (lim>wiped){
          for (u32 ss=wiped;ss<lim;++ss){
            u64* wp=hring+hB+(size_t)(ss&(HD-1))*1024;
#pragma unroll
            for (int i2=0;i2<4;++i2) a_st64(wp+tid+i2*256,SENT64);
          }
          vmw(); __syncthreads();
          if (tid==0) a_st32(hwipe,lim);
          wiped=lim;
        }
      }
    }
  }
}

// ---------------------------------------------------------------------------
__global__ __launch_bounds__(256,1) void lstm_all(
    const float* __restrict__ x,
    const u16* __restrict__ U1p, const u16* __restrict__ U2p,
    const u16* __restrict__ W1p, const u16* __restrict__ W2p,
    const float* __restrict__ b1, const float* __restrict__ b2,
    u64* ring1, u64* ring2, u64* hring, float* hlast, u32* flags)
{
  __shared__ __align__(16) char lds[147456];
  const int bid=blockIdx.x;
  if      (bid<8)  rec_scan<true >(U1p, ring1, hring, flags, nullptr, bid,   lds);
  else if (bid<16) rec_scan<false>(U2p, ring2, hring, flags, hlast,   bid-8, lds);
  else if (bid<24) xw1_prod(x, W1p, b1, ring1, flags, bid-16);
  else             xw2_prod(W2p, b2, hring, ring2, flags, (bid-24)>>1, (bid-24)&1, lds);
}

// ---------------------------------------------------------------------------
__global__ void dense_out(const float* __restrict__ hl, const float* __restrict__ Wd,
                          const float* __restrict__ bd, float* __restrict__ out) {
  int b = blockIdx.x, l = threadIdx.x;
  f32x4 h  = *reinterpret_cast<const f32x4*>(hl + (long)b * NH + l * 4);
  f32x4 wv = *reinterpret_cast<const f32x4*>(Wd + l * 4);
  float s = h[0]*wv[0] + h[1]*wv[1] + h[2]*wv[2] + h[3]*wv[3];
#pragma unroll
  for (int off = 32; off > 0; off >>= 1) s += __shfl_down(s, off);
  if (l == 0) out[b] = fmaxf(s + bd[0], 0.f);
}

// ---------------------------------------------------------------------------
extern "C" void kernel_launch(void* const* d_in, const int* in_sizes, int n_in,
                              void* d_out, int out_size, void* d_ws, size_t ws_size,
                              hipStream_t stream) {
  const float* x  = (const float*)d_in[0];
  const float* W1 = (const float*)d_in[1];
  const float* U1 = (const float*)d_in[2];
  const float* b1 = (const float*)d_in[3];
  const float* W2 = (const float*)d_in[4];
  const float* U2 = (const float*)d_in[5];
  const float* b2 = (const float*)d_in[6];
  const float* Wd = (const float*)d_in[7];
  const float* bd = (const float*)d_in[8];
  float* out = (float*)d_out;

  char* ws = (char*)d_ws;
  size_t off = 0;
  auto alloc = [&](size_t bytes) -> char* {
    char* p = ws + off;
    off = (off + bytes + 255) & ~(size_t)255;
    return p;
  };
  u16* U1p   = (u16*)alloc(512u*1024);
  u16* U2p   = (u16*)alloc(512u*1024);
  u16* W1p   = (u16*)alloc(256u*1024);
  u16* W2p   = (u16*)alloc(512u*1024);
  u64* ring1 = (u64*)alloc((size_t)8*D*8192*8);     // 16 MiB
  u64* ring2 = (u64*)alloc((size_t)8*D*8192*8);     // 16 MiB
  u64* hring = (u64*)alloc((size_t)8*HD*1024*8);    // 4 MiB
  float* hlast = (float*)alloc((size_t)NB*NH*4);
  u32* flags = (u32*)alloc(FLAGS_N*4);

  if (off > ws_size) {
    hipMemsetAsync(d_out, 0x42, (size_t)out_size * sizeof(float), stream);
    return;
  }

  prep_pack<<<320, 256, 0, stream>>>(U1, U2, W1, W2, U1p, U2p, W1p, W2p);
  prep_init<<<2048, 256, 0, stream>>>(hring, flags);
  lstm_all<<<40, 256, 0, stream>>>(x, U1p, U2p, W1p, W2p, b1, b2,
                                   ring1, ring2, hring, hlast, flags);
  dense_out<<<128, 64, 0, stream>>>(hlast, Wd, bd, out);
}

// Round 14
// 9704.477 us; speedup vs baseline: 1.4877x; 1.2810x over previous
//
#include <hip/hip_runtime.h>

typedef __bf16 bf16x8 __attribute__((ext_vector_type(8)));
typedef float  f32x4  __attribute__((ext_vector_type(4)));
typedef unsigned short u16;
typedef unsigned int   u32;
typedef unsigned long long u64;

#define NB 128
#define NT 1024
#define NF 128
#define NH 256
#define NG 1024
#define NBG 16          // groups per layer
#define GR  8           // batch rows per group
#define D   32          // preact ring depth (slots)
#define HD  32          // hring depth (slots)
#define SENT64 (~0ull)

// flags (u32 offsets, 64B-padded)
#define F_PW1(g)  ((g)*16)            // xw1 produced-through (ring1)
#define F_C1(g)   (256+(g)*16)        // L1 rec consumed-through (ring1)
#define F_PW2A(g) (512+(g)*16)        // xw2 p=0 produced (ring2)
#define F_PW2B(g) (768+(g)*16)        // xw2 p=1 produced
#define F_C2(g)   (1024+(g)*16)       // L2 rec consumed (ring2)
#define F_CPA(g)  (1280+(g)*16)       // xw2 p=0 hring consumed
#define F_CPB(g)  (1536+(g)*16)       // xw2 p=1 hring consumed
#define F_HW(g)   (1792+(g)*16)       // hring wiped-through
#define FLAGS_N 2048

__device__ __forceinline__ u16 f2bf(float f){ union{float f;u32 u;}c;c.f=f;u32 u=c.u;return (u16)((u+0x7fffu+((u>>16)&1u))>>16);}
__device__ __forceinline__ float sigm(float x){return 1.f/(1.f+__expf(-x));}
__device__ __forceinline__ float tanh_(float x){return 1.f-2.f/(1.f+__expf(2.f*x));}
__device__ __forceinline__ f32x4 mm(bf16x8 a,bf16x8 b,f32x4 c){return __builtin_amdgcn_mfma_f32_16x16x32_bf16(a,b,c,0,0,0);}
__device__ __forceinline__ u32 a_ld32(const u32*p){return __hip_atomic_load((u32*)p,__ATOMIC_RELAXED,__HIP_MEMORY_SCOPE_AGENT);}
__device__ __forceinline__ u64 a_ld64(const u64*p){return __hip_atomic_load((u64*)p,__ATOMIC_RELAXED,__HIP_MEMORY_SCOPE_AGENT);}
__device__ __forceinline__ void a_st32(u32*p,u32 v){__hip_atomic_store(p,v,__ATOMIC_RELAXED,__HIP_MEMORY_SCOPE_AGENT);}
__device__ __forceinline__ void a_st64(u64*p,u64 v){__hip_atomic_store(p,v,__ATOMIC_RELAXED,__HIP_MEMORY_SCOPE_AGENT);}
__device__ __forceinline__ void vmw(){asm volatile("s_waitcnt vmcnt(0)":::"memory");}

// ---------------------------------------------------------------------------
// prep_pack (R12/13-verbatim, verified): weights fp32 -> bf16 frag packs.
// U: fi=((kt*4+w)*4+gg)*4+ct, col=gg*256+w*64+ct*16+l15.
// W1: fi=(kt*4+w)*16+nt, col=w*256+nt*16+l15.  W2: fi=((p*8+kt)*4+w)*8+nt.
// ---------------------------------------------------------------------------
__global__ void prep_pack(const float* __restrict__ U1,const float* __restrict__ U2,
                          const float* __restrict__ W1,const float* __restrict__ W2,
                          u16* __restrict__ U1p,u16* __restrict__ U2p,
                          u16* __restrict__ W1p,u16* __restrict__ W2p){
  int i = blockIdx.x*256+threadIdx.x;
  if (i < 32768) {
    int lane=i&63, fi=i>>6;
    int ct=fi&3, gg=(fi>>2)&3, w=(fi>>4)&3, kt=fi>>6;
    int col = gg*256 + w*64 + ct*16 + (lane&15);
    int k0  = kt*32 + (lane>>4)*8;
    u16* o1 = U1p + (size_t)fi*512 + lane*8;
    u16* o2 = U2p + (size_t)fi*512 + lane*8;
#pragma unroll
    for (int e=0;e<8;++e){
      o1[e]=f2bf(U1[(size_t)(k0+e)*NG+col]);
      o2[e]=f2bf(U2[(size_t)(k0+e)*NG+col]);
    }
  } else if (i < 49152) {
    int j=i-32768, lane=j&63, fi=j>>6;
    int nt=fi&15, w=(fi>>4)&3, kt=fi>>6;
    int col = w*256 + nt*16 + (lane&15);
    int k0  = kt*32 + (lane>>4)*8;
    u16* o = W1p + (size_t)fi*512 + lane*8;
#pragma unroll
    for (int e=0;e<8;++e) o[e]=f2bf(W1[(size_t)(k0+e)*NG+col]);
  } else if (i < 81920) {
    int j=i-49152, lane=j&63, fi=j>>6;
    int nt=fi&7, w=(fi>>3)&3, kt=(fi>>5)&7, p=fi>>8;
    int col = p*512 + w*128 + nt*16 + (lane&15);
    int k0  = kt*32 + (lane>>4)*8;
    u16* o = W2p + (size_t)fi*512 + lane*8;
#pragma unroll
    for (int e=0;e<8;++e) o[e]=f2bf(W2[(size_t)(k0+e)*NG+col]);
  }
}

// ---------------------------------------------------------------------------
__global__ void prep_init(u64* hring, u32* flags){
  long i = (long)blockIdx.x*256 + threadIdx.x;      // 524288 threads
  if (i < (long)NBG*HD*1024) a_st64(hring+i, SENT64);
  if (i < FLAGS_N) flags[i] = 0;
}

// ---------------------------------------------------------------------------
// rec_scan: single-CU recurrence, U FULLY RESIDENT (kt0..5 regs, kt6..7 LDS).
// 8-row group (rows are independent chains; A rows 8-15 are zeros, discarded).
// Wave w owns unit-cols w*64..+64 of ALL gates -> lane-local pointwise.
// Preacts: bf16 ring, counter-gated, prefetched 1 step ahead into regs.
// h: LDS parity (XOR-swizzled). L1 publishes h to hring (sentinel, f&f).
// ---------------------------------------------------------------------------
template<bool IS1>
__device__ __forceinline__ void rec_scan(
    const u16* __restrict__ Upk, const u64* __restrict__ ring, u64* __restrict__ hring,
    u32* __restrict__ flags, float* __restrict__ hlast, int g, char* lds)
{
  const int tid=threadIdx.x, lane=tid&63, w=tid>>6;
  const int l15=lane&15, l16=lane>>4;

  bf16x8 ufr[6][4][4];
#pragma unroll
  for (int kt=0;kt<6;++kt)
#pragma unroll
    for (int gg=0;gg<4;++gg)
#pragma unroll
      for (int ct=0;ct<4;++ct)
        ufr[kt][gg][ct]=*reinterpret_cast<const bf16x8*>(
            Upk+(size_t)((((kt*4+w)*4+gg)*4)+ct)*512+lane*8);
#pragma unroll
  for (int kt=0;kt<6;++kt)
#pragma unroll
    for (int gg=0;gg<4;++gg)
#pragma unroll
      for (int ct=0;ct<4;++ct)
        asm volatile("" : "+v"(ufr[kt][gg][ct]));

  { // LDS [0,131072): U kt6..7 frag-linear (lds_fi = (kt-6)*64+(w*4+gg)*4+ct)
    const uint4* src=reinterpret_cast<const uint4*>(Upk+(size_t)384*512);
    uint4* dst=reinterpret_cast<uint4*>(lds);
#pragma unroll
    for (int i2=0;i2<32;++i2) dst[tid+i2*256]=src[tid+i2*256];
    // h parity buffers [131072,147456): zero (rows 8-15 stay zero forever)
    uint4 z{0,0,0,0};
    uint4* hz=reinterpret_cast<uint4*>(lds+131072);
#pragma unroll
    for (int i2=0;i2<4;++i2) hz[tid+i2*256]=z;
  }
  __syncthreads();

  u32* progA = flags + (IS1? F_PW1(g):F_PW2A(g));
  u32* progB = flags + F_PW2B(g);
  u32* consP = flags + (IS1? F_C1(g):F_C2(g));
  u32* hwipe = flags + F_HW(g);
  const size_t rB=(size_t)(g*D)*2048;    // ring u64 base
  const size_t hB=(size_t)(g*HD)*1024;   // hring u64 base
  const int pbase = w*512 + l15*2 + (l16&1);
  long budget=3000000;
  u32 avail=0, hwv=0;
  float cst[16]={0.f,0.f,0.f,0.f,0.f,0.f,0.f,0.f,0.f,0.f,0.f,0.f,0.f,0.f,0.f,0.f};
  u64 pr[16];

  { // preload preact slot 0
    while (avail<1u){
      u32 a=a_ld32(progA); if(!IS1){u32 b2=a_ld32(progB); a=a<b2?a:b2;}
      avail=a; if(avail>=1u)break; if(--budget<=0)break;
    }
    asm volatile("":::"memory");
#pragma unroll
    for (int q=0;q<16;++q) pr[q]=a_ld64(ring+rB+(size_t)q*32+pbase);
  }

  for (int t=0;t<NT;++t){
    const int par=t&1;

    // L1: publish h_{t-1} to hring (fire-and-forget; rare hwipe gate)
    if (IS1 && t>0){
      if (t>HD){
        u32 need=(u32)(t-HD);
        while (hwv<need){ hwv=a_ld32(hwipe); if(hwv>=need)break; if(--budget<=0)break; }
        asm volatile("":::"memory");
      }
      const int row=tid>>5, cb=tid&31;
      const char* hp=lds+131072+(par^1)*8192+row*512;
      uint4 q=*reinterpret_cast<const uint4*>(hp+((cb*16)^((row&7)<<4)));
      u64* go=hring+hB+(size_t)((t-1)&(HD-1))*1024+row*64+cb*2;
      a_st64(go,((u64)q.y<<32)|q.x);
      a_st64(go+1,((u64)q.w<<32)|q.z);
    }

    float ia[16];
#pragma unroll
    for (int gg=0;gg<4;++gg){
      f32x4 acc[4]={};
      if (t>0){
#pragma unroll
        for (int kt=0;kt<8;++kt){
          bf16x8 af=*reinterpret_cast<const bf16x8*>(
              lds+131072+(par^1)*8192+l15*512+((kt*64+l16*16)^((l15&7)<<4)));
#pragma unroll
          for (int ct=0;ct<4;++ct){
            bf16x8 bfv;
            if (kt<6) bfv=ufr[kt][gg][ct];
            else bfv=*reinterpret_cast<const bf16x8*>(
                lds+(size_t)((kt-6)*64+(w*4+gg)*4+ct)*1024+lane*16);
            acc[ct]=mm(af,bfv,acc[ct]);
          }
        }
      }
      // add bf16 preacts + fold activation (i -> f -> cbar -> o)
#pragma unroll
      for (int ct=0;ct<4;++ct){
        const u64 q=pr[gg*4+ct];
#pragma unroll
        for (int r=0;r<4;++r){
          float v=acc[ct][r]+__uint_as_float(((u32)((q>>(16*r))&0xffffu))<<16);
          const int o=ct*4+r;
          if      (gg==0) ia[o]=sigm(v);
          else if (gg==1) cst[o]*=sigm(v);
          else if (gg==2) cst[o]+=ia[o]*tanh_(v);
          else {
            float hv=sigm(v)*tanh_(cst[o]);
            if (l16<2){
              const int row=l16*4+r;
              *reinterpret_cast<u16*>(lds+131072+par*8192+row*512+
                  (((w*64+ct*16+l15)*2)^((row&7)<<4)))=f2bf(hv);
              if (!IS1 && t==NT-1)
                hlast[(size_t)(g*GR+row)*NH+w*64+ct*16+l15]=hv;
            }
          }
        }
      }
      // prefetch slot t+1 chunk gg (producers run ~D ahead; gate cached)
      if (t+1<NT){
        if (gg==0 && avail<(u32)(t+2)){
          while (avail<(u32)(t+2)){
            u32 a=a_ld32(progA); if(!IS1){u32 b2=a_ld32(progB); a=a<b2?a:b2;}
            avail=a; if(avail>=(u32)(t+2))break; if(--budget<=0)break;
          }
          asm volatile("":::"memory");
        }
        const size_t nb=rB+(size_t)((t+1)&(D-1))*2048;
#pragma unroll
        for (int ct=0;ct<4;++ct)
          pr[gg*4+ct]=a_ld64(ring+nb+(size_t)(gg*4+ct)*32+pbase);
      }
    }
    __syncthreads();
    if (((t&7)==7) && tid==0) a_st32(consP,(u32)(t+2));
  }

  if (IS1){ // publish final h_{NT-1}
    u32 need=(u32)(NT-HD);
    while (hwv<need){ hwv=a_ld32(hwipe); if(hwv>=need)break; if(--budget<=0)break; }
    asm volatile("":::"memory");
    const int row=tid>>5, cb=tid&31;
    const char* hp=lds+131072+((NT-1)&1)*8192+row*512;
    uint4 q=*reinterpret_cast<const uint4*>(hp+((cb*16)^((row&7)<<4)));
    u64* go=hring+hB+(size_t)((NT-1)&(HD-1))*1024+row*64+cb*2;
    a_st64(go,((u64)q.y<<32)|q.x);
    a_st64(go+1,((u64)q.w<<32)|q.z);
  }
}

// ---------------------------------------------------------------------------
// xw1_prod: ring1[g][t] = x@W1 + b1 (bf16, consumer-register layout).
// ---------------------------------------------------------------------------
__device__ __forceinline__ void xw1_prod(
    const float* __restrict__ x, const u16* __restrict__ Wpk,
    const float* __restrict__ b1, u64* __restrict__ ring,
    u32* __restrict__ flags, int g)
{
  const int tid=threadIdx.x, lane=tid&63, w=tid>>6;
  const int l15=lane&15, l16=lane>>4;
  bf16x8 wfr[4][16];
#pragma unroll
  for (int kt=0;kt<4;++kt)
#pragma unroll
    for (int nt=0;nt<16;++nt)
      wfr[kt][nt]=*reinterpret_cast<const bf16x8*>(Wpk+(size_t)((kt*4+w)*16+nt)*512+lane*8);
#pragma unroll
  for (int kt=0;kt<4;++kt)
#pragma unroll
    for (int nt=0;nt<16;++nt) asm volatile("" : "+v"(wfr[kt][nt]));
  float bb[16];
#pragma unroll
  for (int nt=0;nt<16;++nt) bb[nt]=b1[w*256+nt*16+l15];

  u32* consP=flags+F_C1(g); u32* prog=flags+F_PW1(g);
  const size_t rB=(size_t)(g*D)*2048;
  const size_t xrow=(size_t)(g*GR+(l15&7))*NT;   // rows 8-15 dup row (discarded)
  long budget=3000000; u32 consc=0;

  for (int t=0;t<NT;++t){
    if (t>=D){
      u32 need=(u32)(t-30);
      while (consc<need){ consc=a_ld32(consP); if(consc>=need)break; if(--budget<=0)break; }
      asm volatile("":::"memory");
    }
    bf16x8 ax[4];
    const float* xp0=x+(xrow+t)*NF;
#pragma unroll
    for (int kt=0;kt<4;++kt){
      f32x4 x0=*reinterpret_cast<const f32x4*>(xp0+kt*32+l16*8);
      f32x4 x1=*reinterpret_cast<const f32x4*>(xp0+kt*32+l16*8+4);
      union{u16 s2[8];bf16x8 v;}cv;
#pragma unroll
      for (int e=0;e<4;++e){cv.s2[e]=f2bf(x0[e]);cv.s2[4+e]=f2bf(x1[e]);}
      ax[kt]=cv.v;
    }
    f32x4 acc[16];
#pragma unroll
    for (int nt=0;nt<16;++nt) acc[nt]=f32x4{bb[nt],bb[nt],bb[nt],bb[nt]};
#pragma unroll
    for (int kt=0;kt<4;++kt)
#pragma unroll
      for (int nt=0;nt<16;++nt) acc[nt]=mm(ax[kt],wfr[kt][nt],acc[nt]);
    if (l16<2){
      const size_t sb=rB+(size_t)(t&(D-1))*2048;
#pragma unroll
      for (int nt=0;nt<16;++nt){
        union{u16 s2[4];u64 q;}pk;
#pragma unroll
        for (int r=0;r<4;++r) pk.s2[r]=f2bf(acc[nt][r]);
        const size_t idx=(size_t)((nt>>2)*16+w*4+(nt&3))*32+l15*2+l16;
        a_st64(ring+sb+idx,pk.q);
      }
    }
    if ((t&7)==7){ vmw(); __syncthreads(); if(tid==0) a_st32(prog,(u32)(t+1)); }
  }
}

// ---------------------------------------------------------------------------
// xw2_prod: ring2[g][t] half-p = hring[g][t]@W2 + b2. hring sentinel-consumed
// with speculative next-slot prefetch; p=0 wipes consumed slots.
// ---------------------------------------------------------------------------
__device__ __forceinline__ void xw2_prod(
    const u16* __restrict__ Wpk, const float* __restrict__ b2,
    u64* __restrict__ hring, u64* __restrict__ ring2,
    u32* __restrict__ flags, int g, int p, char* lds)
{
  const int tid=threadIdx.x, lane=tid&63, w=tid>>6;
  const int l15=lane&15, l16=lane>>4;
  bf16x8 wfr[8][8];
#pragma unroll
  for (int kt=0;kt<8;++kt)
#pragma unroll
    for (int nt=0;nt<8;++nt)
      wfr[kt][nt]=*reinterpret_cast<const bf16x8*>(Wpk+(size_t)(((p*8+kt)*4+w)*8+nt)*512+lane*8);
#pragma unroll
  for (int kt=0;kt<8;++kt)
#pragma unroll
    for (int nt=0;nt<8;++nt) asm volatile("" : "+v"(wfr[kt][nt]));
  float bb[8];
#pragma unroll
  for (int nt=0;nt<8;++nt) bb[nt]=b2[p*512+w*128+nt*16+l15];

  u32* consP=flags+F_C2(g);
  u32* prog = flags+(p?F_PW2B(g):F_PW2A(g));
  u32* mycp = flags+(p?F_CPB(g):F_CPA(g));
  u32* otcp = flags+(p?F_CPA(g):F_CPB(g));
  u32* hwipe= flags+F_HW(g);
  const size_t rB=(size_t)(g*D)*2048;
  const size_t hB=(size_t)(g*HD)*1024;
  long budget=3000000; u32 consc=0, wiped=0;

  u64 hr[8][2];
  { const u64* hb=hring+hB+(size_t)l15*64;
#pragma unroll
    for (int kt=0;kt<8;++kt){ hr[kt][0]=a_ld64(hb+kt*8+l16*2); hr[kt][1]=a_ld64(hb+kt*8+l16*2+1); }
  }

  for (int t=0;t<NT;++t){
    if (t>=D){
      u32 need=(u32)(t-30);
      while (consc<need){ consc=a_ld32(consP); if(consc>=need)break; if(--budget<=0)break; }
      asm volatile("":::"memory");
    }
    const u64* hb=hring+hB+(size_t)(t&(HD-1))*1024+(size_t)l15*64;
    { // sentinel check (rows 8-15 stay sentinel: predicate l15<8)
      bool ok;
      if (l15>=8) ok=true;
      else { ok=true;
#pragma unroll
        for (int kt=0;kt<8;++kt) ok=ok&&(hr[kt][0]!=SENT64)&&(hr[kt][1]!=SENT64); }
      while (!__all(ok?1:0)){
        if (--budget<=0) break;
#pragma unroll
        for (int kt=0;kt<8;++kt){ hr[kt][0]=a_ld64(hb+kt*8+l16*2); hr[kt][1]=a_ld64(hb+kt*8+l16*2+1); }
        if (l15>=8) ok=true;
        else { ok=true;
#pragma unroll
          for (int kt=0;kt<8;++kt) ok=ok&&(hr[kt][0]!=SENT64)&&(hr[kt][1]!=SENT64); }
      }
      asm volatile("":::"memory");
    }
    f32x4 acc[8];
#pragma unroll
    for (int nt=0;nt<8;++nt) acc[nt]=f32x4{bb[nt],bb[nt],bb[nt],bb[nt]};
#pragma unroll
    for (int kt=0;kt<8;++kt){
      union{u64 q[2];bf16x8 v;}cv; cv.q[0]=hr[kt][0]; cv.q[1]=hr[kt][1];
#pragma unroll
      for (int nt=0;nt<8;++nt) acc[nt]=mm(cv.v,wfr[kt][nt],acc[nt]);
    }
    if (t+1<NT){ // speculative prefetch of next slot
      const u64* nhb=hring+hB+(size_t)((t+1)&(HD-1))*1024+(size_t)l15*64;
#pragma unroll
      for (int kt=0;kt<8;++kt){ hr[kt][0]=a_ld64(nhb+kt*8+l16*2); hr[kt][1]=a_ld64(nhb+kt*8+l16*2+1); }
    }
    if (l16<2){
      const size_t sb=rB+(size_t)(t&(D-1))*2048;
      const int gg=p*2+(w>>1);
#pragma unroll
      for (int nt=0;nt<8;++nt){
        union{u16 s2[4];u64 q;}pk;
#pragma unroll
        for (int r=0;r<4;++r) pk.s2[r]=f2bf(acc[nt][r]);
        const int cw=(w*2+(nt>>2))&3;
        const size_t idx=(size_t)(cw*16+gg*4+(nt&3))*32+l15*2+l16;
        a_st64(ring2+sb+idx,pk.q);
      }
    }
    if ((t&7)==7){
      vmw(); __syncthreads();
      if (tid==0){ a_st32(prog,(u32)(t+1)); a_st32(mycp,(u32)(t+1)); }
      if (p==0){
        volatile u32* sh=(volatile u32*)lds;
        if (tid==0){ u32 oc=a_ld32(otcp); u32 lim=oc<(u32)(t+1)?oc:(u32)(t+1); sh[0]=lim; }
        __syncthreads();
        u32 lim=sh[0];
        if (lim>wiped){
          for (u32 ss=wiped;ss<lim;++ss){
            u64* wp=hring+hB+(size_t)(ss&(HD-1))*1024+tid*2;
            a_st64(wp,SENT64); a_st64(wp+1,SENT64);
          }
          vmw(); __syncthreads();
          if (tid==0) a_st32(hwipe,lim);
          wiped=lim;
        }
      }
    }
  }
}

// ---------------------------------------------------------------------------
__global__ __launch_bounds__(256,1) void lstm_all(
    const float* __restrict__ x,
    const u16* __restrict__ U1p, const u16* __restrict__ U2p,
    const u16* __restrict__ W1p, const u16* __restrict__ W2p,
    const float* __restrict__ b1, const float* __restrict__ b2,
    u64* ring1, u64* ring2, u64* hring, float* hlast, u32* flags)
{
  __shared__ __align__(16) char lds[147456];
  const int bid=blockIdx.x;
  if      (bid<16) rec_scan<true >(U1p, ring1, hring, flags, nullptr, bid,    lds);
  else if (bid<32) rec_scan<false>(U2p, ring2, hring, flags, hlast,   bid-16, lds);
  else if (bid<48) xw1_prod(x, W1p, b1, ring1, flags, bid-32);
  else             xw2_prod(W2p, b2, hring, ring2, flags, (bid-48)>>1, (bid-48)&1, lds);
}

// ---------------------------------------------------------------------------
__global__ void dense_out(const float* __restrict__ hl, const float* __restrict__ Wd,
                          const float* __restrict__ bd, float* __restrict__ out) {
  int b = blockIdx.x, l = threadIdx.x;
  f32x4 h  = *reinterpret_cast<const f32x4*>(hl + (long)b * NH + l * 4);
  f32x4 wv = *reinterpret_cast<const f32x4*>(Wd + l * 4);
  float s = h[0]*wv[0] + h[1]*wv[1] + h[2]*wv[2] + h[3]*wv[3];
#pragma unroll
  for (int off = 32; off > 0; off >>= 1) s += __shfl_down(s, off);
  if (l == 0) out[b] = fmaxf(s + bd[0], 0.f);
}

// ---------------------------------------------------------------------------
extern "C" void kernel_launch(void* const* d_in, const int* in_sizes, int n_in,
                              void* d_out, int out_size, void* d_ws, size_t ws_size,
                              hipStream_t stream) {
  const float* x  = (const float*)d_in[0];
  const float* W1 = (const float*)d_in[1];
  const float* U1 = (const float*)d_in[2];
  const float* b1 = (const float*)d_in[3];
  const float* W2 = (const float*)d_in[4];
  const float* U2 = (const float*)d_in[5];
  const float* b2 = (const float*)d_in[6];
  const float* Wd = (const float*)d_in[7];
  const float* bd = (const float*)d_in[8];
  float* out = (float*)d_out;

  char* ws = (char*)d_ws;
  size_t off = 0;
  auto alloc = [&](size_t bytes) -> char* {
    char* p = ws + off;
    off = (off + bytes + 255) & ~(size_t)255;
    return p;
  };
  u16* U1p   = (u16*)alloc(512u*1024);
  u16* U2p   = (u16*)alloc(512u*1024);
  u16* W1p   = (u16*)alloc(256u*1024);
  u16* W2p   = (u16*)alloc(512u*1024);
  u64* ring1 = (u64*)alloc((size_t)NBG*D*2048*8);    // 8 MiB
  u64* ring2 = (u64*)alloc((size_t)NBG*D*2048*8);    // 8 MiB
  u64* hring = (u64*)alloc((size_t)NBG*HD*1024*8);   // 4 MiB
  float* hlast = (float*)alloc((size_t)NB*NH*4);
  u32* flags = (u32*)alloc(FLAGS_N*4);

  if (off > ws_size) {
    hipMemsetAsync(d_out, 0x42, (size_t)out_size * sizeof(float), stream);
    return;
  }

  prep_pack<<<320, 256, 0, stream>>>(U1, U2, W1, W2, U1p, U2p, W1p, W2p);
  prep_init<<<2048, 256, 0, stream>>>(hring, flags);
  lstm_all<<<80, 256, 0, stream>>>(x, U1p, U2p, W1p, W2p, b1, b2,
                                   ring1, ring2, hring, hlast, flags);
  dense_out<<<128, 64, 0, stream>>>(hlast, Wd, bd, out);
}

// Round 15
// 5667.405 us; speedup vs baseline: 2.5474x; 1.7123x over previous
//
#include <hip/hip_runtime.h>

typedef __bf16 bf16x8 __attribute__((ext_vector_type(8)));
typedef float  f32x4  __attribute__((ext_vector_type(4)));
typedef unsigned short u16;
typedef unsigned int   u32;
typedef unsigned long long u64;

#define NB 128      // batch
#define NT 1024     // time steps
#define NF 128      // input features
#define NH 256      // hidden units
#define NG 1024     // 4*NH gate columns
#define M_ROWS (NB*NT)
#define SENT (~0ull)   // sentinel: 4x bf16 0xFFFF (NaN) -- unreachable as h data

__device__ __forceinline__ u16 f2bf(float f) {
  union { float f; u32 u; } c; c.f = f;
  u32 u = c.u;
  return (u16)((u + 0x7fffu + ((u >> 16) & 1u)) >> 16);   // RNE
}
__device__ __forceinline__ float sigm(float x) { return 1.f / (1.f + __expf(-x)); }
__device__ __forceinline__ float tanh_(float x) { return 1.f - 2.f / (1.f + __expf(2.f * x)); }
__device__ __forceinline__ f32x4 mm(bf16x8 a, bf16x8 b, f32x4 c) {
  return __builtin_amdgcn_mfma_f32_16x16x32_bf16(a, b, c, 0, 0, 0);
}

// Relaxed AGENT atomics: MALL coherence point by scope, no cache-maintenance.
// (HW-proven data path, rounds 4-14.)
__device__ __forceinline__ u64 a_ld64(const u64* p) { return __hip_atomic_load((u64*)p, __ATOMIC_RELAXED, __HIP_MEMORY_SCOPE_AGENT); }
__device__ __forceinline__ void a_st64(u64* p, u64 v) { __hip_atomic_store(p, v, __ATOMIC_RELAXED, __HIP_MEMORY_SCOPE_AGENT); }

// ---------------------------------------------------------------------------
// prep: sentinel-fill hseq (64 MiB) + h2 (256 KiB). Runs every launch ->
// also erases stale data from prior replays.
// ---------------------------------------------------------------------------
__global__ void prep(u64* __restrict__ hseq, u64* __restrict__ h2) {
  long i = (long)blockIdx.x * 256 + threadIdx.x;
  if (i < (long)M_ROWS * 64) a_st64(hseq + i, SENT);
  if (i < 4L * 8 * 16 * 64)  a_st64(h2 + i, SENT);
}

// ---------------------------------------------------------------------------
// Fused 2-layer LSTM scan, SENTINEL protocol with gl double-buffered by step
// parity -> ONE barrier per step.
//   producer: a_st64 h chunks, fire-and-forget.
//   consumer: poll the data words themselves until != SENT (detect == data).
// Buffers: hseq [NB,NT,NH] bf16 write-once; h2 4-deep [4][8][16][NH] bf16,
// each L2 WG re-sentinels its chunk of slot (t+1)&3 per step.
// 64 WGs: bid<32 -> L1, else L2; 8 groups x 4 WGs x 4 waves (wave = gate).
// ---------------------------------------------------------------------------
template<bool IS1>
__device__ void scan(const float* __restrict__ U, const float* __restrict__ W,
                     const float* __restrict__ bias, const float* __restrict__ xf,
                     u64* hseq, u64* h2, float* hlast,
                     int g, int j, float (*gl)[4][16][68])
{
  const int tid = threadIdx.x, lane = tid & 63, w = tid >> 6;
  const int l15 = lane & 15, l16 = lane >> 4;
  constexpr int KIN  = IS1 ? NF : NH;
  constexpr int KTIN = KIN / 32;
  const int colb = w * NH + j * 64;

  // Resident W frags (B-operand), K = KIN
  bf16x8 wfr[KTIN][4];
#pragma unroll
  for (int kt = 0; kt < KTIN; ++kt) {
    const int k0 = kt * 32 + l16 * 8;
#pragma unroll
    for (int nt = 0; nt < 4; ++nt) {
      const float* wp = W + (long)k0 * NG + colb + nt * 16 + l15;
      union { u16 s[8]; bf16x8 v; } cv;
#pragma unroll
      for (int e = 0; e < 8; ++e) cv.s[e] = f2bf(wp[(long)e * NG]);
      wfr[kt][nt] = cv.v;
    }
  }
  // Resident U frags (B-operand), K = NH
  bf16x8 ufr[8][4];
#pragma unroll
  for (int kt = 0; kt < 8; ++kt) {
    const int k0 = kt * 32 + l16 * 8;
#pragma unroll
    for (int nt = 0; nt < 4; ++nt) {
      const float* up = U + (long)k0 * NG + colb + nt * 16 + l15;
      union { u16 s[8]; bf16x8 v; } cv;
#pragma unroll
      for (int e = 0; e < 8; ++e) cv.s[e] = f2bf(up[(long)e * NG]);
      ufr[kt][nt] = cv.v;
    }
  }
  // Pin frags (unified VGPR/AGPR file; prevents remat-by-reload).
#pragma unroll
  for (int kt = 0; kt < KTIN; ++kt)
#pragma unroll
    for (int nt = 0; nt < 4; ++nt)
      asm volatile("" : "+v"(wfr[kt][nt]));
#pragma unroll
  for (int kt = 0; kt < 8; ++kt)
#pragma unroll
    for (int nt = 0; nt < 4; ++nt)
      asm volatile("" : "+v"(ufr[kt][nt]));

  const int prow = tid & 15, ublk = tid >> 4;
  const int b = g * 16 + prow, ucol = j * 64 + ublk * 4;

  float bv[4][4];
#pragma unroll
  for (int gg = 0; gg < 4; ++gg)
#pragma unroll
    for (int q = 0; q < 4; ++q) bv[gg][q] = bias[gg * NH + ucol + q];

  const long abatch = (long)(g * 16 + l15) * NT;

  float cst[4] = {0.f, 0.f, 0.f, 0.f};
  long budget = 500000;   // poll iterations; bail, never hang

  for (int t = 0; t < NT; ++t) {
    bf16x8 ax[KTIN];
    f32x4 acc[4] = {};
    const int p = t & 1;   // gl parity

    if constexpr (IS1) {
      // ---- x loads + cvt + x@W MFMAs (overlaps producers' store flight) ----
      const float* xp0 = xf + (abatch + t) * NF;
      f32x4 xraw[KTIN][2];
#pragma unroll
      for (int kt = 0; kt < KTIN; ++kt) {
        const float* xp = xp0 + kt * 32 + l16 * 8;
        xraw[kt][0] = *reinterpret_cast<const f32x4*>(xp);
        xraw[kt][1] = *reinterpret_cast<const f32x4*>(xp + 4);
      }
#pragma unroll
      for (int kt = 0; kt < KTIN; ++kt) {
        union { u16 s[8]; bf16x8 v; } cv;
#pragma unroll
        for (int e = 0; e < 4; ++e) {
          cv.s[e] = f2bf(xraw[kt][0][e]); cv.s[4 + e] = f2bf(xraw[kt][1][e]);
        }
        ax[kt] = cv.v;
      }
#pragma unroll
      for (int kt = 0; kt < KTIN; ++kt)
#pragma unroll
        for (int nt = 0; nt < 4; ++nt) acc[nt] = mm(ax[kt], wfr[kt][nt], acc[nt]);

      // ---- sentinel-poll h_{t-1} (detect == data) + U MFMAs ----
      if (t > 0) {
        const u64* hb = hseq + (abatch + (t - 1)) * 64;
        u64 hr[8][2];
        for (;;) {
          bool ok = true;
#pragma unroll
          for (int kt = 0; kt < 8; ++kt) {
            hr[kt][0] = a_ld64(hb + kt * 8 + l16 * 2);
            hr[kt][1] = a_ld64(hb + kt * 8 + l16 * 2 + 1);
          }
#pragma unroll
          for (int kt = 0; kt < 8; ++kt)
            ok = ok && (hr[kt][0] != SENT) && (hr[kt][1] != SENT);
          if (__all(ok ? 1 : 0)) break;
          if (--budget <= 0) break;
        }
        asm volatile("" ::: "memory");
#pragma unroll
        for (int kt = 0; kt < 8; ++kt) {
          union { u64 q[2]; bf16x8 v; } cv;
          cv.q[0] = hr[kt][0]; cv.q[1] = hr[kt][1];
#pragma unroll
          for (int nt = 0; nt < 4; ++nt) acc[nt] = mm(cv.v, ufr[kt][nt], acc[nt]);
        }
      }
    } else {
      // ---- L2: ONE sentinel-poll over feed (hseq[t]) + rec (h2 slot) ----
      const u64* xb = hseq + (abatch + t) * 64;
      const u64* hb = h2 + (((long)((t + 3) & 3) * 8 + g) * 16 + l15) * 64;
      u64 xr[8][2], hr[8][2];
      for (;;) {
        bool ok = true;
#pragma unroll
        for (int kt = 0; kt < 8; ++kt) {
          xr[kt][0] = a_ld64(xb + kt * 8 + l16 * 2);
          xr[kt][1] = a_ld64(xb + kt * 8 + l16 * 2 + 1);
        }
#pragma unroll
        for (int kt = 0; kt < 8; ++kt)
          ok = ok && (xr[kt][0] != SENT) && (xr[kt][1] != SENT);
        if (t > 0) {
#pragma unroll
          for (int kt = 0; kt < 8; ++kt) {
            hr[kt][0] = a_ld64(hb + kt * 8 + l16 * 2);
            hr[kt][1] = a_ld64(hb + kt * 8 + l16 * 2 + 1);
          }
#pragma unroll
          for (int kt = 0; kt < 8; ++kt)
            ok = ok && (hr[kt][0] != SENT) && (hr[kt][1] != SENT);
        }
        if (__all(ok ? 1 : 0)) break;
        if (--budget <= 0) break;
      }
      asm volatile("" ::: "memory");
#pragma unroll
      for (int kt = 0; kt < KTIN; ++kt) {
        union { u64 q[2]; bf16x8 v; } cv;
        cv.q[0] = xr[kt][0]; cv.q[1] = xr[kt][1];
        ax[kt] = cv.v;
      }
#pragma unroll
      for (int kt = 0; kt < KTIN; ++kt)
#pragma unroll
        for (int nt = 0; nt < 4; ++nt) acc[nt] = mm(ax[kt], wfr[kt][nt], acc[nt]);
      if (t > 0) {
#pragma unroll
        for (int kt = 0; kt < 8; ++kt) {
          union { u64 q[2]; bf16x8 v; } cv;
          cv.q[0] = hr[kt][0]; cv.q[1] = hr[kt][1];
#pragma unroll
          for (int nt = 0; nt < 4; ++nt) acc[nt] = mm(cv.v, ufr[kt][nt], acc[nt]);
        }
      }
    }

    // ---- gate tiles -> LDS (cross-wave exchange), parity-buffered ----
    // One barrier/step: step t+2's writes to parity p are separated from
    // step t's reads of parity p by step t+1's barrier (each wave's t+1
    // writes follow its t reads in program order).
#pragma unroll
    for (int nt = 0; nt < 4; ++nt)
#pragma unroll
      for (int r = 0; r < 4; ++r)
        gl[p][w][l16 * 4 + r][nt * 16 + l15] = acc[nt][r];
    __syncthreads();
    f32x4 gi = *reinterpret_cast<const f32x4*>(&gl[p][0][prow][ublk * 4]);
    f32x4 gf = *reinterpret_cast<const f32x4*>(&gl[p][1][prow][ublk * 4]);
    f32x4 gc = *reinterpret_cast<const f32x4*>(&gl[p][2][prow][ublk * 4]);
    f32x4 go = *reinterpret_cast<const f32x4*>(&gl[p][3][prow][ublk * 4]);

    // ---- pointwise cell update (Keras order i, f, cbar, o) ----
    float hh[4];
#pragma unroll
    for (int q = 0; q < 4; ++q) {
      float iv = sigm(gi[q] + bv[0][q]);
      float fv = sigm(gf[q] + bv[1][q]);
      float cd = tanh_(gc[q] + bv[2][q]);
      float ov = sigm(go[q] + bv[3][q]);
      cst[q] = fv * cst[q] + iv * cd;
      hh[q] = ov * tanh_(cst[q]);
    }
    union { u16 s[4]; u64 q; } hp;
#pragma unroll
    for (int q = 0; q < 4; ++q) hp.s[q] = f2bf(hh[q]);

    // ---- publish h_t: fire-and-forget atomic store ----
    if constexpr (IS1) {
      a_st64(hseq + ((long)b * NT + t) * 64 + (ucol >> 2), hp.q);
    } else {
      a_st64(h2 + (((long)(t & 3) * 8 + g) * 16 + prow) * 64 + (ucol >> 2), hp.q);
      // wipe own chunk of slot (t+1)&3 (holds t-3 data; readers provably done)
      a_st64(h2 + (((long)((t + 1) & 3) * 8 + g) * 16 + prow) * 64 + (ucol >> 2), SENT);
      if (t == NT - 1)
        *reinterpret_cast<f32x4*>(hlast + (long)b * NH + ucol) =
            f32x4{hh[0], hh[1], hh[2], hh[3]};
    }
  }
}

// ---------------------------------------------------------------------------
__global__ __launch_bounds__(256, 1) void lstm_fused(
    const float* __restrict__ x,
    const float* __restrict__ W1, const float* __restrict__ U1, const float* __restrict__ b1,
    const float* __restrict__ W2, const float* __restrict__ U2, const float* __restrict__ b2,
    u64* hseq, u64* h2, float* hlast)
{
  __shared__ __align__(16) float gl[2][4][16][68];   // parity double-buffer
  const int bid = blockIdx.x;
  const int sb  = bid & 31, g = sb & 7, j = sb >> 3;
  if (bid < 32)
    scan<true >(U1, W1, b1, x, hseq, h2, nullptr, g, j, gl);
  else
    scan<false>(U2, W2, b2, nullptr, hseq, h2, hlast, g, j, gl);
}

// ---------------------------------------------------------------------------
__global__ void dense_out(const float* __restrict__ hl, const float* __restrict__ Wd,
                          const float* __restrict__ bd, float* __restrict__ out) {
  int b = blockIdx.x, l = threadIdx.x;
  f32x4 h  = *reinterpret_cast<const f32x4*>(hl + (long)b * NH + l * 4);
  f32x4 wv = *reinterpret_cast<const f32x4*>(Wd + l * 4);
  float s = h[0] * wv[0] + h[1] * wv[1] + h[2] * wv[2] + h[3] * wv[3];
#pragma unroll
  for (int off = 32; off > 0; off >>= 1) s += __shfl_down(s, off);
  if (l == 0) out[b] = fmaxf(s + bd[0], 0.f);
}

// ---------------------------------------------------------------------------
extern "C" void kernel_launch(void* const* d_in, const int* in_sizes, int n_in,
                              void* d_out, int out_size, void* d_ws, size_t ws_size,
                              hipStream_t stream) {
  const float* x  = (const float*)d_in[0];
  const float* W1 = (const float*)d_in[1];
  const float* U1 = (const float*)d_in[2];
  const float* b1 = (const float*)d_in[3];
  const float* W2 = (const float*)d_in[4];
  const float* U2 = (const float*)d_in[5];
  const float* b2 = (const float*)d_in[6];
  const float* Wd = (const float*)d_in[7];
  const float* bd = (const float*)d_in[8];
  float* out = (float*)d_out;

  char* ws = (char*)d_ws;
  size_t off = 0;
  auto alloc = [&](size_t bytes) -> char* {
    char* p = ws + off;
    off = (off + bytes + 255) & ~(size_t)255;
    return p;
  };
  u64*   hseq  = (u64*)  alloc((size_t)M_ROWS * NH * 2);       // 64 MiB
  u64*   h2    = (u64*)  alloc((size_t)4 * 8 * 16 * NH * 2);   // 256 KiB
  float* hlast = (float*)alloc((size_t)NB * NH * 4);           // 128 KiB

  if (off > ws_size) {
    // workspace too small: finite sentinel 0x42424242 ~= 48.56 (NOT NaN)
    hipMemsetAsync(d_out, 0x42, (size_t)out_size * sizeof(float), stream);
    return;
  }

  prep<<<32768, 256, 0, stream>>>(hseq, h2);
  lstm_fused<<<64, 256, 0, stream>>>(x, W1, U1, b1, W2, U2, b2, hseq, h2, hlast);
  dense_out<<<128, 64, 0, stream>>>(hlast, Wd, bd, out);
}